// Round 8
// baseline (188.351 us; speedup 1.0000x reference)
//
#include <hip/hip_runtime.h>
#include <stdint.h>

typedef unsigned long long u64;
typedef unsigned int u32;

#define N_ANCH 36864
#define WGRID 64
#define A_PER 9
#define KTOP 6000
#define NOUT 300
#define NBIN 3072       // monotone distribution-aware bins (max used = 2304)
#define NSLICE 36
#define NCHK 94         // ceil(6000/64)
#define INF_BIN 0

// Base anchors from py-faster-rcnn generate_anchors (scales 8,16,32; ratios .5,1,2), exact integers.
__constant__ float c_ax1[9] = {-84.f,-176.f,-360.f,-56.f,-120.f,-248.f,-36.f,-80.f,-168.f};
__constant__ float c_ay1[9] = {-40.f,-88.f,-184.f,-56.f,-120.f,-248.f,-80.f,-168.f,-344.f};
__constant__ float c_aw[9]  = {184.f,368.f,736.f,128.f,256.f,512.f,88.f,176.f,352.f};
__constant__ float c_ah[9]  = {96.f,192.f,384.f,128.f,256.f,512.f,176.f,352.f,704.f};

// Monotone (order-preserving) bin of ordered-float score word u. Scores
// sigmoid(l1-l0) concentrate in [0.5,1] = one float octave -> 2049 fine bins.
__device__ __forceinline__ u32 binof(u32 u) {
    if (u < 0x80000000u) return 0u;                               // -inf (invalid)
    if (u < 0xBF000000u) return 1u + ((u - 0x80000000u) >> 22);   // s<0.5 : 1..252
    return 256u + ((u - 0xBF000000u) >> 12);                      // s>=0.5: 256..2304
}

// 8x8 grid of 128-px cells occupancy signature. Exact-safe NMS prefilter:
// sig-disjoint => x- or y-ranges disjoint => iw<1 or ih<1 => IoU < 1/31 < 0.7.
__device__ __forceinline__ u64 sigof(float4 b) {
    int cx0 = (int)b.x >> 7, cx1 = (int)b.z >> 7;
    int cy0 = (int)b.y >> 7, cy1 = (int)b.w >> 7;
    u32 colm = (2u << cx1) - (1u << cx0);
    u64 rowsel = ((~0ULL) >> (8 * (7 - cy1))) & ((~0ULL) << (8 * cy0));
    return rowsel & (0x0101010101010101ULL * (u64)colm);
}

__device__ __forceinline__ u64 shfl64(u64 v, int src) {
    u32 lo = (u32)__shfl((int)(v & 0xFFFFFFFFu), src, 64);
    u32 hi = (u32)__shfl((int)(v >> 32), src, 64);
    return ((u64)hi << 32) | lo;
}

__device__ __forceinline__ bool iou_gt(float4 a, float areaA, float4 b, float areaB) {
    float ix1 = fmaxf(a.x, b.x), iy1 = fmaxf(a.y, b.y);
    float ix2 = fminf(a.z, b.z), iy2 = fminf(a.w, b.w);
    float iw = fmaxf(ix2 - ix1 + 1.0f, 0.0f);
    float ih = fmaxf(iy2 - iy1 + 1.0f, 0.0f);
    float inter = iw * ih;
    float iou = inter / (areaA + areaB - inter);
    return iou > 0.7f;
}

// K1: 36 blocks x 1024 = one thread per anchor. Per-block private hist slice,
// stored TRANSPOSED (slicesT[bin*36 + blk]) so K2's merge is coalesced uint4 loads.
__global__ __launch_bounds__(1024) void proposal_kernel(const float* __restrict__ cls,
                                                        const float* __restrict__ dlt,
                                                        u32* __restrict__ ords,
                                                        float4* __restrict__ boxes,
                                                        u32* __restrict__ slicesT) {
    __shared__ u32 lh[NBIN];
    const int t = threadIdx.x;
    for (int b = t; b < NBIN; b += 1024) lh[b] = 0;
    __syncthreads();

    const int i = (int)blockIdx.x * 1024 + t;
    int a  = i % A_PER;
    int hw = i / A_PER;
    int wx = hw % WGRID;
    int hy = hw / WGRID;

    float l0 = cls[hw * 18 + 2 * a];
    float l1 = cls[hw * 18 + 2 * a + 1];
    float m  = fmaxf(l0, l1);
    float e0 = expf(l0 - m), e1 = expf(l1 - m);
    float s  = e1 / (e0 + e1);

    const float* d = dlt + hw * 36 + 4 * a;
    float dx = d[0], dy = d[1], dw = d[2], dh = d[3];
    float aw = c_aw[a], ah = c_ah[a];
    float axc = (c_ax1[a] + 16.f * (float)wx) + 0.5f * aw;
    float ayc = (c_ay1[a] + 16.f * (float)hy) + 0.5f * ah;
    float pxc = dx * aw + axc;
    float pyc = dy * ah + ayc;
    float pw  = expf(dw) * aw;
    float ph  = expf(dh) * ah;
    float x1 = pxc - 0.5f * pw, y1 = pyc - 0.5f * ph;
    float x2 = pxc + 0.5f * pw, y2 = pyc + 0.5f * ph;
    x1 = fminf(fmaxf(x1, 0.f), 1023.f);
    x2 = fminf(fmaxf(x2, 0.f), 1023.f);
    y1 = fminf(fmaxf(y1, 0.f), 1023.f);
    y2 = fminf(fmaxf(y2, 0.f), 1023.f);
    bool valid = ((x2 - x1 + 1.f) >= 16.f) && ((y2 - y1 + 1.f) >= 16.f);
    float sc = valid ? s : -__builtin_huge_valf();

    u32 sb  = __float_as_uint(sc);
    u32 ord = (sb & 0x80000000u) ? ~sb : (sb | 0x80000000u);
    ords[i]  = ord;
    boxes[i] = make_float4(x1, y1, x2, y2);

    u64 infb = __ballot(!valid);
    if (valid) {
        atomicAdd(&lh[binof(ord)], 1u);
    } else if ((t & 63) == __builtin_ctzll(infb)) {
        atomicAdd(&lh[INF_BIN], (u32)__popcll(infb));
    }
    __syncthreads();
    for (int b = t; b < NBIN; b += 1024)
        slicesT[b * NSLICE + (int)blockIdx.x] = lh[b];
}

// K2: single block, 1024 threads. merge-hist -> scan -> scatter -> rank -> NMS -> out.
__global__ __launch_bounds__(1024) void select_nms_kernel(const u32* __restrict__ ords,
                                                          const float4* __restrict__ boxes,
                                                          const u32* __restrict__ slicesT,
                                                          u64* __restrict__ scat,
                                                          float4* __restrict__ topBoxes,
                                                          float* __restrict__ out) {
    __shared__ u32 sBinStart[NBIN];
    __shared__ u32 sHist[NBIN];
    __shared__ u32 sCursor[NBIN];     // also fallback-scan scratch
    __shared__ u32 swsum[16];
    __shared__ u64 intra[2][64];
    __shared__ u64 supw[16];
    __shared__ u64 keepw[NCHK];
    __shared__ float4 kbox[NOUT];
    __shared__ float  karea[NOUT];
    __shared__ u64    ksig[NOUT];
    __shared__ int sE, sV, s_nkept, s_oldn;

    const int t = threadIdx.x;
    const int lane = t & 63;
    const int w = t >> 6;             // 16 waves

    // ---- A: merge 36 transposed slices (coalesced uint4), descending exclusive scan ----
    if (t == 0) { sV = KTOP; sE = KTOP; s_nkept = 0; s_oldn = 0; }
    if (t < NCHK) keepw[t] = 0;
    if (t < 64) { intra[0][t] = 0; intra[1][t] = 0; }
    const int hi = NBIN - 1 - 3 * t;  // thread t owns bins hi, hi-1, hi-2 (descending)
    u32 cnt[3];
#pragma unroll
    for (int q = 0; q < 3; ++q) {
        const int b = hi - q;
        const uint4* p4 = (const uint4*)(slicesT + b * NSLICE);   // 144 B, 16B-aligned
        u32 acc = 0;
#pragma unroll
        for (int j = 0; j < NSLICE / 4; ++j) {
            uint4 v = p4[j];
            acc += v.x + v.y + v.z + v.w;
        }
        cnt[q] = acc;
        sHist[b] = acc;
    }
    u32 sum3 = cnt[0] + cnt[1] + cnt[2];
    u32 x = sum3;                     // wave-inclusive scan (shfl, no barriers)
    for (int d = 1; d < 64; d <<= 1) {
        u32 y = __shfl_up(x, d, 64);
        if (lane >= d) x += y;
    }
    if (lane == 63) swsum[w] = x;
    for (int b = t; b < NBIN; b += 1024) sCursor[b] = 0;
    __syncthreads();
    if (t == 0) {
        u32 run0 = 0;
        for (int q = 0; q < 16; ++q) { u32 v = swsum[q]; swsum[q] = run0; run0 += v; }
    }
    __syncthreads();
    u32 run = swsum[w] + x - sum3;    // sum of all higher bins (exclusive)
#pragma unroll
    for (int q = 0; q < 3; ++q) {
        const int b = hi - q;
        u32 e = run + cnt[q];
        sBinStart[b] = run;
        if (run < KTOP && e >= KTOP) sE = (int)e;   // unique boundary bucket
        run = e;
    }
    __syncthreads();

    // ---- B: scatter keys of buckets starting before rank KTOP ----
    for (int i2 = t; i2 < N_ANCH; i2 += 1024) {
        u32 ov = ords[i2];
        u32 b = binof(ov);
        u32 s0 = sBinStart[b];
        if (s0 < KTOP) {
            u32 pos = s0 + atomicAdd(&sCursor[b], 1u);
            scat[pos] = ((u64)ov << 32) | (u32)(~(u32)i2);
        }
    }
    __syncthreads();

    // ---- C: exact rank within bucket (keys unique), gather topBoxes[rank], find V ----
    const int E = sE;
    for (int i2 = t; i2 < E; i2 += 1024) {
        u64 k = scat[i2];
        u32 b = binof((u32)(k >> 32));
        u32 s0 = sBinStart[b], c = sHist[b];
        u32 r = s0;
        for (u32 j = s0; j < s0 + c; ++j) r += (scat[j] > k) ? 1u : 0u;
        if (r < (u32)KTOP) {
            int idx = (int)(~(u32)k);
            topBoxes[r] = boxes[idx];
            if (!(k >> 63)) atomicMin(&sV, (int)r);   // first -inf rank => V
        }
    }
    __syncthreads();

    // ---- D: greedy NMS. Kept sigs in registers (lane s of wave w = kept w+16s);
    //      shfl broadcasts replace per-kept LDS reads; IoU only on sig-hit. ----
    const int V = sV;
    const int nchunks = (V + 63) >> 6;
    u64 myksig = 0;

    for (int c = 0; c < nchunks; ++c) {
        const int p = c & 1;
        const int base = c * 64;
        const int csz = min(64, V - base);
        float4 bb = make_float4(0.f, 0.f, 0.f, 0.f);
        if (lane < csz) bb = topBoxes[base + lane];       // L1-hot, all 16 waves
        float ab = (bb.z - bb.x + 1.f) * (bb.w - bb.y + 1.f);
        u64 sg = sigof(bb);
        const int nk = s_nkept;
        // sup-by-kept: wave w covers kept k ≡ w (mod 16); sig from regs via shfl
        bool sup = false;
        int s = 0;
        for (int k = w; k < nk; k += 16, ++s) {
            u64 sigk = shfl64(myksig, s);
            if (sg & sigk) {
                float4 kb4 = kbox[k];
                float ka = karea[k];
                if (iou_gt(bb, ab, kb4, ka)) { sup = true; break; }
            }
        }
        if (lane >= csz) sup = false;
        u64 bal = __ballot(sup);
        if (lane == 0) supw[w] = bal;
        if (w == 14 && c + 1 < nchunks) intra[p ^ 1][lane] = 0;  // zero next buffer
        // intra-chunk pairs: wave w covers jj ∈ {w, w+16, w+32, w+48}, data via shfl
        u64 m = 0;
#pragma unroll
        for (int q = 0; q < 4; ++q) {
            int jj = w + 16 * q;
            u64 sgj = shfl64(sg, jj);
            float jx1 = __shfl(bb.x, jj, 64);
            float jy1 = __shfl(bb.y, jj, 64);
            float jx2 = __shfl(bb.z, jj, 64);
            float jy2 = __shfl(bb.w, jj, 64);
            float ja  = __shfl(ab,   jj, 64);
            if (lane < jj && jj < csz && (sg & sgj)) {
                float4 bj = make_float4(jx1, jy1, jx2, jy2);
                if (iou_gt(bb, ab, bj, ja)) m |= (1ULL << jj);
            }
        }
        if (m) atomicOr(&intra[p][lane], m);
        __syncthreads();                                  // B1: supw + intra ready
        if (w == 0) {
            u64 row = intra[p][lane];
            u64 sup64 = supw[0];
#pragma unroll
            for (int q = 1; q < 16; ++q) sup64 |= supw[q];
            u64 alive = ~sup64;
            if (csz < 64) alive &= ((1ULL << csz) - 1ULL);
            u64 cand = alive, kb = 0;
            const int nk0 = s_nkept;
            int nk2 = nk0;
            while (cand && nk2 < NOUT) {
                int b = __builtin_ctzll(cand);
                cand &= cand - 1;
                kb |= (1ULL << b);
                ++nk2;
                cand &= ~shfl64(row, b);
            }
            if ((kb >> lane) & 1ULL) {                    // append kept in rank order
                int pos = nk0 + __popcll(kb & ((1ULL << lane) - 1ULL));
                kbox[pos]  = bb;
                karea[pos] = ab;
                ksig[pos]  = sg;
            }
            if (lane == 0) { keepw[c] = kb; s_oldn = nk0; s_nkept = nk2; }
        }
        __syncthreads();                                  // B2: kept state visible
        const int newn = s_nkept, oldn = s_oldn;
        for (int pos = oldn; pos < newn; ++pos) {         // pull new sigs into regs
            if ((pos & 15) == w) {
                u64 v = ksig[pos];
                if (lane == (pos >> 4)) myksig = v;
            }
        }
        if (newn >= NOUT) break;
    }

    // ---- E: output blob (+ -inf tie fallback, ascending rank) ----
    const int n1 = s_nkept;
    for (int r = t; r < n1; r += 1024) {
        float4 b = kbox[r];
        out[r * 5 + 0] = 0.f;
        out[r * 5 + 1] = b.x; out[r * 5 + 2] = b.y;
        out[r * 5 + 3] = b.z; out[r * 5 + 4] = b.w;
    }
    if (n1 < NOUT) {
        __syncthreads();
        const int per = 6;                                // 1024*6 >= 6000
        int r0 = t * per, r1 = min(r0 + per, KTOP);
        u32 cntk = 0;
        for (int r = r0; r < r1; ++r)
            cntk += ((keepw[r >> 6] >> (r & 63)) & 1ULL) ? 0u : 1u;
        sCursor[t] = cntk;
        __syncthreads();
        for (int dd = 1; dd < 1024; dd <<= 1) {
            u32 v = (t >= dd) ? sCursor[t - dd] : 0;
            __syncthreads();
            sCursor[t] += v;
            __syncthreads();
        }
        int ord2 = n1 + (int)(sCursor[t] - cntk);         // exclusive prefix of not-kept
        for (int r = r0; r < r1 && ord2 < NOUT; ++r) {
            if (!((keepw[r >> 6] >> (r & 63)) & 1ULL)) {
                float4 b = topBoxes[r];
                out[ord2 * 5 + 0] = 0.f;
                out[ord2 * 5 + 1] = b.x; out[ord2 * 5 + 2] = b.y;
                out[ord2 * 5 + 3] = b.z; out[ord2 * 5 + 4] = b.w;
                ++ord2;
            }
        }
    }
}

extern "C" void kernel_launch(void* const* d_in, const int* in_sizes, int n_in,
                              void* d_out, int out_size, void* d_ws, size_t ws_size,
                              hipStream_t stream) {
    const float* cls = (const float*)d_in[0];   // (1,64,64,18) f32
    const float* dlt = (const float*)d_in[1];   // (1,64,64,36) f32
    float* out = (float*)d_out;                 // 300x5 f32
    char* ws = (char*)d_ws;
    u32*    ordsArr  = (u32*)   (ws);                    // 147456
    u64*    scat     = (u64*)   (ws + 147456);           // 294912
    float4* boxes    = (float4*)(ws + 442368);           // 589824
    float4* topBoxes = (float4*)(ws + 1032192);          // 96000
    u32*    slicesT  = (u32*)   (ws + 1128192);          // 36*3072*4 = 442368 (transposed)

    proposal_kernel<<<NSLICE, 1024, 0, stream>>>(cls, dlt, ordsArr, boxes, slicesT);
    select_nms_kernel<<<1, 1024, 0, stream>>>(ordsArr, boxes, slicesT, scat, topBoxes, out);
}

// Round 9
// 155.576 us; speedup vs baseline: 1.2107x; 1.2107x over previous
//
#include <hip/hip_runtime.h>
#include <stdint.h>

typedef unsigned long long u64;
typedef unsigned int u32;

#define N_ANCH 36864
#define WGRID 64
#define A_PER 9
#define KTOP 6000
#define NOUT 300
#define NBIN 3072       // monotone distribution-aware bins (max used = 2304)
#define NCHK 94         // ceil(6000/64)
#define ORD_NEGINF 0x007FFFFFu   // ord bits of -inf score (invalid box)

// Base anchors from py-faster-rcnn generate_anchors (scales 8,16,32; ratios .5,1,2), exact integers.
__constant__ float c_ax1[9] = {-84.f,-176.f,-360.f,-56.f,-120.f,-248.f,-36.f,-80.f,-168.f};
__constant__ float c_ay1[9] = {-40.f,-88.f,-184.f,-56.f,-120.f,-248.f,-80.f,-168.f,-344.f};
__constant__ float c_aw[9]  = {184.f,368.f,736.f,128.f,256.f,512.f,88.f,176.f,352.f};
__constant__ float c_ah[9]  = {96.f,192.f,384.f,128.f,256.f,512.f,176.f,352.f,704.f};

// Monotone (order-preserving) bin of ordered-float score word u. Scores
// sigmoid(l1-l0) concentrate in [0.5,1] = one float octave -> 2049 fine bins.
__device__ __forceinline__ u32 binof(u32 u) {
    if (u < 0x80000000u) return 0u;                               // -inf (invalid)
    if (u < 0xBF000000u) return 1u + ((u - 0x80000000u) >> 22);   // s<0.5 : 1..252
    return 256u + ((u - 0xBF000000u) >> 12);                      // s>=0.5: 256..2304
}

// 8x8 grid of 128-px cells occupancy signature. Exact prefilter: sig-disjoint
// => cell-rects disjoint => x- or y-pixel ranges disjoint => intersection = 0.
__device__ __forceinline__ u64 sigof(float4 b) {
    int cx0 = (int)b.x >> 7, cx1 = (int)b.z >> 7;
    int cy0 = (int)b.y >> 7, cy1 = (int)b.w >> 7;
    u32 colm = (2u << cx1) - (1u << cx0);
    u64 rowsel = ((~0ULL) >> (8 * (7 - cy1))) & ((~0ULL) << (8 * cy0));
    return rowsel & (0x0101010101010101ULL * (u64)colm);
}

__device__ __forceinline__ u64 shfl64(u64 v, int src) {
    u32 lo = (u32)__shfl((int)(v & 0xFFFFFFFFu), src, 64);
    u32 hi = (u32)__shfl((int)(v >> 32), src, 64);
    return ((u64)hi << 32) | lo;
}

__device__ __forceinline__ bool iou_gt(float4 a, float areaA, float4 b, float areaB) {
    float ix1 = fmaxf(a.x, b.x), iy1 = fmaxf(a.y, b.y);
    float ix2 = fminf(a.z, b.z), iy2 = fminf(a.w, b.w);
    float iw = fmaxf(ix2 - ix1 + 1.0f, 0.0f);
    float ih = fmaxf(iy2 - iy1 + 1.0f, 0.0f);
    float inter = iw * ih;
    float iou = inter / (areaA + areaB - inter);
    return iou > 0.7f;
}

// K1: 36 blocks x 1024 = one thread per anchor. Pure proposal math; no histogram.
__global__ __launch_bounds__(1024) void proposal_kernel(const float* __restrict__ cls,
                                                        const float* __restrict__ dlt,
                                                        u32* __restrict__ ords,
                                                        float4* __restrict__ boxes) {
    const int i = (int)blockIdx.x * 1024 + threadIdx.x;
    int a  = i % A_PER;
    int hw = i / A_PER;
    int wx = hw % WGRID;
    int hy = hw / WGRID;

    // softmax over 2 logits, class-1 prob (matches jax.nn.softmax: subtract max)
    float l0 = cls[hw * 18 + 2 * a];
    float l1 = cls[hw * 18 + 2 * a + 1];
    float m  = fmaxf(l0, l1);
    float e0 = expf(l0 - m), e1 = expf(l1 - m);
    float s  = e1 / (e0 + e1);

    const float* d = dlt + hw * 36 + 4 * a;
    float dx = d[0], dy = d[1], dw = d[2], dh = d[3];
    float aw = c_aw[a], ah = c_ah[a];
    float axc = (c_ax1[a] + 16.f * (float)wx) + 0.5f * aw;
    float ayc = (c_ay1[a] + 16.f * (float)hy) + 0.5f * ah;
    float pxc = dx * aw + axc;
    float pyc = dy * ah + ayc;
    float pw  = expf(dw) * aw;
    float ph  = expf(dh) * ah;
    float x1 = pxc - 0.5f * pw, y1 = pyc - 0.5f * ph;
    float x2 = pxc + 0.5f * pw, y2 = pyc + 0.5f * ph;
    x1 = fminf(fmaxf(x1, 0.f), 1023.f);
    x2 = fminf(fmaxf(x2, 0.f), 1023.f);
    y1 = fminf(fmaxf(y1, 0.f), 1023.f);
    y2 = fminf(fmaxf(y2, 0.f), 1023.f);
    bool valid = ((x2 - x1 + 1.f) >= 16.f) && ((y2 - y1 + 1.f) >= 16.f);
    float sc = valid ? s : -__builtin_huge_valf();

    u32 sb  = __float_as_uint(sc);
    u32 ord = (sb & 0x80000000u) ? ~sb : (sb | 0x80000000u);
    ords[i]  = ord;
    boxes[i] = make_float4(x1, y1, x2, y2);
}

// K2: single block, 1024 threads. hist -> scan -> scatter -> rank -> NMS -> out.
__global__ __launch_bounds__(1024) void select_nms_kernel(const u32* __restrict__ ords,
                                                          const float4* __restrict__ boxes,
                                                          u64* __restrict__ scat,
                                                          float4* __restrict__ topBoxes,
                                                          float* __restrict__ out) {
    __shared__ u32 sHist[NBIN];
    __shared__ u32 sBinStart[NBIN];
    __shared__ u32 sCursor[NBIN];     // also fallback-scan scratch
    __shared__ u32 swsum[16];
    __shared__ float4 cbox[2][64];
    __shared__ float  ca[2][64];
    __shared__ u64    csig[2][64];
    __shared__ u64    intra[2][64];
    __shared__ u64    supw[16];
    __shared__ u64    keepw[NCHK];
    __shared__ float4 kbox[NOUT];
    __shared__ float  karea[NOUT];
    __shared__ u64    ksig[NOUT];
    __shared__ int    sE, s_nkept;

    const int t = threadIdx.x;
    const int lane = t & 63;
    const int w = t >> 6;             // 16 waves

    for (int b = t; b < NBIN; b += 1024) { sHist[b] = 0; sCursor[b] = 0; }
    if (t == 0) { sE = KTOP; s_nkept = 0; }
    if (t < NCHK) keepw[t] = 0;
    if (t < 64) { intra[0][t] = 0; intra[1][t] = 0; }
    __syncthreads();

    // ---- H: LDS histogram from ords (coalesced; -inf bin wave-aggregated) ----
    for (int i2 = t; i2 < N_ANCH; i2 += 1024) {     // N_ANCH % 1024 == 0: all lanes active
        u32 ov = ords[i2];
        bool inf0 = (ov == ORD_NEGINF);
        u64 bi = __ballot(inf0);
        if (inf0) {
            if (lane == __builtin_ctzll(bi))
                atomicAdd(&sHist[0], (u32)__popcll(bi));
        } else {
            atomicAdd(&sHist[binof(ov)], 1u);
        }
    }
    __syncthreads();

    // ---- S: descending exclusive scan over 3072 bins (3 bins/thread) ----
    const int hi = NBIN - 1 - 3 * t;
    u32 cnt[3];
    cnt[0] = sHist[hi]; cnt[1] = sHist[hi - 1]; cnt[2] = sHist[hi - 2];
    u32 sum3 = cnt[0] + cnt[1] + cnt[2];
    u32 x = sum3;                     // wave-inclusive scan (shfl, no barriers)
    for (int d = 1; d < 64; d <<= 1) {
        u32 y = __shfl_up(x, d, 64);
        if (lane >= d) x += y;
    }
    if (lane == 63) swsum[w] = x;
    __syncthreads();
    if (t == 0) {
        u32 run0 = 0;
        for (int q = 0; q < 16; ++q) { u32 v = swsum[q]; swsum[q] = run0; run0 += v; }
    }
    __syncthreads();
    u32 run = swsum[w] + x - sum3;    // sum of all higher bins (exclusive)
#pragma unroll
    for (int q = 0; q < 3; ++q) {
        const int b = hi - q;
        u32 e = run + cnt[q];
        sBinStart[b] = run;
        if (run < KTOP && e >= KTOP) sE = (int)e;   // unique boundary bucket
        run = e;
    }
    __syncthreads();
    const int E = sE;
    const int V = min(KTOP, (int)sBinStart[0]);     // sBinStart[0] = #finite-score keys

    // ---- SC: scatter keys of buckets starting before rank KTOP (global scat) ----
    for (int i2 = t; i2 < N_ANCH; i2 += 1024) {
        u32 ov = ords[i2];
        u32 b = binof(ov);
        u32 s0 = sBinStart[b];
        if (s0 < KTOP) {
            u32 pos = s0 + atomicAdd(&sCursor[b], 1u);
            scat[pos] = ((u64)ov << 32) | (u32)(~(u32)i2);
        }
    }
    __syncthreads();

    // ---- R: exact rank within bucket (keys unique), gather topBoxes[rank] ----
    for (int i2 = t; i2 < E; i2 += 1024) {
        u64 k = scat[i2];
        u32 b = binof((u32)(k >> 32));
        u32 s0 = sBinStart[b], c = sHist[b];
        u32 r = s0;
        for (u32 j = s0; j < s0 + c; ++j) r += (scat[j] > k) ? 1u : 0u;
        if (r < (u32)KTOP) topBoxes[r] = boxes[(int)(~(u32)k)];
    }
    __syncthreads();

    // ---- D: greedy NMS (round-5 structure: LDS staging, dbuf, w0-resolve || w1-stage,
    //      2 barriers/chunk) + LDS ksig prefilter; scans have NO break -> pipelined ----
    const int nchunks = (V + 63) >> 6;
    if (t < 64) {                      // stage chunk 0
        float4 b = make_float4(0.f, 0.f, 0.f, 0.f);
        if (t < V) b = topBoxes[t];
        cbox[0][t] = b;
        ca[0][t]   = (b.z - b.x + 1.f) * (b.w - b.y + 1.f);
        csig[0][t] = sigof(b);
    }
    __syncthreads();

    for (int c = 0; c < nchunks; ++c) {
        const int p = c & 1;
        const int base = c * 64;
        const int csz = min(64, V - base);
        const int nk = s_nkept;
        // w1 issues next-chunk prefetch early (latency hidden behind sup scan)
        float4 preb = make_float4(0.f, 0.f, 0.f, 0.f);
        if (w == 1) {
            int nb = base + 64 + lane;
            if (nb < V) preb = topBoxes[nb];
        }
        bool sup = false;
        u64 m = 0;
        if (lane < csz) {
            float4 bb = cbox[p][lane]; float ab = ca[p][lane]; u64 sg = csig[p][lane];
            // sup-by-kept: wave w covers kept k ≡ w (mod 16); no break -> unrolled
#pragma unroll 4
            for (int k = w; k < nk; k += 16) {
                if ((sg & ksig[k]) && iou_gt(bb, ab, kbox[k], karea[k])) sup = true;
            }
            // intra-chunk pairs: slice w covers j>lane with j%16==w (max 4 iters)
            int j0 = lane + 1;
            j0 += ((w - j0) % 16 + 16) % 16;
            for (int j = j0; j < csz; j += 16)
                if ((sg & csig[p][j]) && iou_gt(bb, ab, cbox[p][j], ca[p][j]))
                    m |= (1ULL << j);
        }
        u64 bal = __ballot(sup);
        if (lane == 0) supw[w] = bal;
        if (m) atomicOr(&intra[p][lane], m);
        __syncthreads();                                  // B1: supw + intra ready
        if (w == 0) {
            // greedy resolve: rows in wave-0 lane registers, broadcast via shfl
            u64 row = intra[p][lane];
            u64 sup64 = supw[0];
#pragma unroll
            for (int q = 1; q < 16; ++q) sup64 |= supw[q];
            u64 alive = ~sup64;
            if (csz < 64) alive &= ((1ULL << csz) - 1ULL);
            u64 cand = alive, kb = 0;
            const int nk0 = s_nkept;
            int nk2 = nk0;
            while (cand && nk2 < NOUT) {
                int b = __builtin_ctzll(cand);
                cand &= cand - 1;
                kb |= (1ULL << b);
                ++nk2;
                cand &= ~shfl64(row, b);
            }
            if ((kb >> lane) & 1ULL) {                    // append kept in rank order
                int pos = nk0 + __popcll(kb & ((1ULL << lane) - 1ULL));
                kbox[pos]  = cbox[p][lane];
                karea[pos] = ca[p][lane];
                ksig[pos]  = csig[p][lane];
            }
            if (lane == 0) { keepw[c] = kb; s_nkept = nk2; }
        } else if (w == 1) {
            // stage next chunk (regs -> LDS) concurrently with resolve
            cbox[p ^ 1][lane] = preb;
            ca[p ^ 1][lane]   = (preb.z - preb.x + 1.f) * (preb.w - preb.y + 1.f);
            csig[p ^ 1][lane] = sigof(preb);
            intra[p ^ 1][lane] = 0;
        }
        __syncthreads();                                  // B2: kept state + stage visible
        if (s_nkept >= NOUT) break;
    }

    // ---- E: output blob (+ -inf tie fallback, ascending rank) ----
    const int n1 = s_nkept;
    for (int r = t; r < n1; r += 1024) {
        float4 b = kbox[r];
        out[r * 5 + 0] = 0.f;
        out[r * 5 + 1] = b.x; out[r * 5 + 2] = b.y;
        out[r * 5 + 3] = b.z; out[r * 5 + 4] = b.w;
    }
    if (n1 < NOUT) {
        __syncthreads();
        const int per = 6;                                // 1024*6 >= 6000
        int r0 = t * per, r1 = min(r0 + per, KTOP);
        u32 cntk = 0;
        for (int r = r0; r < r1; ++r)
            cntk += ((keepw[r >> 6] >> (r & 63)) & 1ULL) ? 0u : 1u;
        sCursor[t] = cntk;
        __syncthreads();
        for (int dd = 1; dd < 1024; dd <<= 1) {
            u32 v = (t >= dd) ? sCursor[t - dd] : 0;
            __syncthreads();
            sCursor[t] += v;
            __syncthreads();
        }
        int ord2 = n1 + (int)(sCursor[t] - cntk);         // exclusive prefix of not-kept
        for (int r = r0; r < r1 && ord2 < NOUT; ++r) {
            if (!((keepw[r >> 6] >> (r & 63)) & 1ULL)) {
                float4 b = topBoxes[r];
                out[ord2 * 5 + 0] = 0.f;
                out[ord2 * 5 + 1] = b.x; out[ord2 * 5 + 2] = b.y;
                out[ord2 * 5 + 3] = b.z; out[ord2 * 5 + 4] = b.w;
                ++ord2;
            }
        }
    }
}

extern "C" void kernel_launch(void* const* d_in, const int* in_sizes, int n_in,
                              void* d_out, int out_size, void* d_ws, size_t ws_size,
                              hipStream_t stream) {
    const float* cls = (const float*)d_in[0];   // (1,64,64,18) f32
    const float* dlt = (const float*)d_in[1];   // (1,64,64,36) f32
    float* out = (float*)d_out;                 // 300x5 f32
    char* ws = (char*)d_ws;
    u32*    ordsArr  = (u32*)   (ws);                    // 147456
    u64*    scat     = (u64*)   (ws + 147456);           // 294912 (sized N_ANCH: no overflow)
    float4* boxes    = (float4*)(ws + 442368);           // 589824
    float4* topBoxes = (float4*)(ws + 1032192);          // 96000

    proposal_kernel<<<36, 1024, 0, stream>>>(cls, dlt, ordsArr, boxes);
    select_nms_kernel<<<1, 1024, 0, stream>>>(ordsArr, boxes, scat, topBoxes, out);
}